// Round 3
// baseline (611.276 us; speedup 1.0000x reference)
//
#include <hip/hip_runtime.h>
#include <hip/hip_bf16.h>
#include <math.h>

#define N_   128
#define C_   64
#define T_   256
#define V_   25
#define D_   64
#define CTV  409600   // C*T*V
#define TV   6400     // T*V

typedef __attribute__((ext_vector_type(8))) short short8;
typedef __attribute__((ext_vector_type(4))) short short4v;
typedef __attribute__((ext_vector_type(4))) float f32x4;

typedef __attribute__((address_space(1))) unsigned uag;
typedef __attribute__((address_space(3))) unsigned ual;
// global->LDS direct DMA, 16B per lane; LDS dest must be linear in lane order.
// Generic->AS3 truncation trick is the CK-proven formulation.
#define GLD16(gp, lp) __builtin_amdgcn_global_load_lds( \
    (uag*)(unsigned long long)(gp), (ual*)(unsigned)(unsigned long long)(lp), 16, 0, 0)

__device__ inline unsigned short f2b(float f) {
    __hip_bfloat16 h = __float2bfloat16(f);
    return *(unsigned short*)&h;
}
__device__ inline float b2f(unsigned short u) {
    return __uint_as_float(((unsigned)u) << 16);
}

// ---------------- K1: pooled[n*64+c] = mean over (t,v); also emit bf16 pre-swizzled x ----------------
// xb16 layout: [n][chunk=t/4][c][tl*25+v]  -> each (n,chunk) slab = 64*100 u16 = 12800B contiguous.
__global__ __launch_bounds__(256) void k_pool(const float* __restrict__ x0,
                                              float* __restrict__ pooled,
                                              unsigned short* __restrict__ xb16) {
    const int bid = blockIdx.x;            // n*64 + c  (plane of 6400 contiguous floats)
    const int tid = threadIdx.x;
    const int n = bid >> 6, c = bid & 63;
    const float4* base = (const float4*)(x0 + (size_t)bid * TV);
    float s = 0.f;
    for (int i = tid; i < 1600; i += 256) {
        float4 f = base[i];
        s += (f.x + f.y) + (f.z + f.w);
        int flat = i * 4;                          // t*25+v, never crosses a 100-elem chunk row
        int chunk = flat / 100;
        int within = flat - chunk * 100;
        short4v pk = { (short)f2b(f.x), (short)f2b(f.y), (short)f2b(f.z), (short)f2b(f.w) };
        *(short4v*)(xb16 + ((size_t)((n * 64 + chunk) * 64 + c)) * 100 + within) = pk;
    }
    #pragma unroll
    for (int off = 32; off > 0; off >>= 1) s += __shfl_down(s, off);
    __shared__ float red[4];
    if ((tid & 63) == 0) red[tid >> 6] = s;
    __syncthreads();
    if (tid == 0) pooled[bid] = (red[0] + red[1] + red[2] + red[3]) * (1.0f / TV);
}

// ---------------- K2: SE gate -> Wfb (bf16, B-frag order), bfv; mask-pair precompute ----------------
// Wfb[n] flat index e = ((w*2+s)*64 + lane)*8 + j  <->  B[c = s*32 + (lane>>4)*8 + j][d = w*16 + (lane&15)]
// shift_in is a rotation (c'=c, v'=(v+c)%25) -> only packed mask pairs mgp[v*32+cp] needed.
__global__ __launch_bounds__(256) void k_se(
    const float* __restrict__ pooled, const float* __restrict__ fc1w,
    const float* __restrict__ fc1b,  const float* __restrict__ fc2w,
    const float* __restrict__ fc2b,  const float* __restrict__ Wm,
    const float* __restrict__ bm,    const float* __restrict__ mask,
    const int* __restrict__ ep,
    unsigned short* __restrict__ Wfb, float* __restrict__ bfv,
    unsigned* __restrict__ mgp)
{
    __shared__ float sp[64], sh[16], sl[4];
    __shared__ float wk[64 * 65];          // W[k] staged [c][d] padded (+1)
    const int tid = threadIdx.x, n = blockIdx.x;
    if (tid < 64) sp[tid] = pooled[n * 64 + tid];
    __syncthreads();
    if (tid < 16) {
        float s = fc1b[tid];
        #pragma unroll
        for (int c = 0; c < 64; c++) s = fmaf(sp[c], fc1w[tid * 64 + c], s);
        sh[tid] = fmaxf(s, 0.f);
    }
    __syncthreads();
    if (tid < 4) {
        float s = fc2b[tid];
        #pragma unroll
        for (int j = 0; j < 16; j++) s = fmaf(sh[j], fc2w[tid * 16 + j], s);
        sl[tid] = s;
    }
    __syncthreads();
    const int e = ep[0];
    const float tao = (e >= 60) ? 1.0f : (-(29.0f / 60.0f) * (float)e + 30.0f);
    const float it = 1.0f / tao;
    float l0 = sl[0] * it, l1 = sl[1] * it, l2 = sl[2] * it, l3 = sl[3] * it;
    float mx = fmaxf(fmaxf(l0, l1), fmaxf(l2, l3));
    float e0 = expf(l0 - mx), e1 = expf(l1 - mx), e2 = expf(l2 - mx), e3 = expf(l3 - mx);
    float inv = 1.0f / (e0 + e1 + e2 + e3);
    float ga[4] = {e0 * inv, e1 * inv, e2 * inv, e3 * inv};

    float accW[16];
    #pragma unroll
    for (int m = 0; m < 16; m++) accW[m] = 0.f;
    #pragma unroll
    for (int k = 0; k < 4; k++) {
        __syncthreads();
        for (int i = tid; i < 4096; i += 256)       // coalesced read of W[k] ([c][d])
            wk[(i >> 6) * 65 + (i & 63)] = Wm[k * 4096 + i];
        __syncthreads();
        #pragma unroll
        for (int m = 0; m < 16; m++) {
            int o = m * 256 + tid;                   // frag-order flat index
            int w  = o >> 10, s = (o >> 9) & 1;
            int ln = (o >> 3) & 63, j = o & 7;
            int c  = s * 32 + (ln >> 4) * 8 + j;
            int d  = w * 16 + (ln & 15);
            accW[m] = fmaf(ga[k], wk[c * 65 + d], accW[m]);
        }
    }
    #pragma unroll
    for (int m = 0; m < 16; m++)
        Wfb[(size_t)n * 4096 + m * 256 + tid] = f2b(accW[m]);   // coalesced shorts
    if (tid < 64)
        bfv[n * 64 + tid] = ga[0] * bm[tid] + ga[1] * bm[64 + tid] +
                            ga[2] * bm[128 + tid] + ga[3] * bm[192 + tid];
    if (n == 0) {
        for (int j2 = tid; j2 < 800; j2 += 256) {   // j2 = v*32 + cp, c = 2*cp
            int v = j2 >> 5, c = (j2 & 31) * 2;
            unsigned m0 = (unsigned)f2b(tanhf(mask[v * 64 + c]) + 1.0f);
            unsigned m1 = (unsigned)f2b(tanhf(mask[v * 64 + c + 1]) + 1.0f);
            mgp[j2] = (m1 << 16) | m0;
        }
    }
}

// ---------------- K3: MFMA main: y = rot-gather(xb16)*mg @ Wf + bf, + BN stats ----------------
// Stage via global_load_lds DMA from pre-swizzled xb16 (linear LDS). Next sub's DMA is issued
// after the gather barrier so it hides under the MFMA phase (T14). 2 barriers/sub as before.
// shift-in gather: src v' = (v + c) mod 25, src c' = c  (closed-form rotation).
__global__ __launch_bounds__(256, 4) void k_main(
    const unsigned short* __restrict__ xb16, const unsigned short* __restrict__ Wfb,
    const float* __restrict__ bfv, const unsigned* __restrict__ mgp,
    __hip_bfloat16* __restrict__ y, float* __restrict__ sn)
{
    __shared__ __align__(16) unsigned short xs[6400];   // bf16 slab [c][tl*25+v] (4 t's), linear
    __shared__ unsigned short At[7616];    // A-tile: 112 rows x 68 (stride 68 kills conflicts)
    __shared__ unsigned mgS[800];          // packed mask bf16 pairs [v][cp]

    const int tid = threadIdx.x;
    const int w = tid >> 6, l = tid & 63, q = l >> 4, m = l & 15;
    const int n = blockIdx.x >> 4;
    const int tbase = (blockIdx.x & 15) * 16;
    const int chunk0 = (blockIdx.x & 15) * 4;

    // B fragments (held whole kernel) + bias
    short8 bf0 = *(const short8*)(Wfb + (size_t)n * 4096 + (w * 2 + 0) * 512 + l * 8);
    short8 bf1 = *(const short8*)(Wfb + (size_t)n * 4096 + (w * 2 + 1) * 512 + l * 8);
    const int d = w * 16 + m;
    const float bfl = bfv[n * 64 + d];

    for (int i = tid; i < 800; i += 256) mgS[i] = mgp[i];
    // zero the 12 pad rows (v = 25..27 image): rho = 96 + t*4 + vr, vr in 1..3
    for (int i = tid; i < 408; i += 256) {
        int rr = i / 34, wo = i - rr * 34;
        int t = rr / 3, vr = rr - t * 3 + 1;
        ((unsigned*)At)[(96 + t * 4 + vr) * 34 + wo] = 0u;
    }
    {   // prologue: DMA sub 0 (12800B contiguous -> xs linear)
        const unsigned short* slab = xb16 + (size_t)(n * 64 + chunk0) * 6400;
        for (int i = tid; i < 800; i += 256)
            GLD16((const unsigned*)slab + i * 4, (unsigned*)xs + i * 4);
    }

    float ss[25], sq[25];
    #pragma unroll
    for (int v = 0; v < 25; v++) { ss[v] = 0.f; sq[v] = 0.f; }

    for (int sub = 0; sub < 4; sub++) {
        const int t0 = tbase + sub * 4;
        __syncthreads();   // xs(sub) DMA drained (vmcnt0 before barrier); prev At consumed
        // rotation gather + mask -> At (bf16 pairs)
        for (int p = tid; p < 3200; p += 256) {
            int cp = p & 31, rv = p >> 5;          // rv = t*25 + v
            int t = rv / 25, v = rv - t * 25;
            int c = cp * 2;
            unsigned mg = mgS[v * 32 + cp];
            int v0 = (v + c) % 25;
            int v1 = v0 + 1; if (v1 == 25) v1 = 0;
            float x0v = b2f(xs[c * 100 + t * 25 + v0])       * b2f((unsigned short)(mg & 0xffff));
            float x1v = b2f(xs[(c + 1) * 100 + t * 25 + v1]) * b2f((unsigned short)(mg >> 16));
            int rho = (v >> 2) * 16 + t * 4 + (v & 3);
            *(unsigned*)&At[rho * 68 + c] = ((unsigned)f2b(x1v) << 16) | f2b(x0v);
        }
        __syncthreads();   // At ready; xs free -> prefetch next slab under MFMA
        if (sub < 3) {
            const unsigned short* slab = xb16 + (size_t)(n * 64 + chunk0 + sub + 1) * 6400;
            for (int i = tid; i < 800; i += 256)
                GLD16((const unsigned*)slab + i * 4, (unsigned*)xs + i * 4);
        }
        // MFMA: 7 M-tiles x 2 k-steps; epilogue per tile
        #pragma unroll
        for (int tau = 0; tau < 7; tau++) {
            const unsigned short* Ab = At + (tau * 16 + m) * 68 + q * 8;
            short4v a0l = *(const short4v*)(Ab);
            short4v a0h = *(const short4v*)(Ab + 4);
            short4v a1l = *(const short4v*)(Ab + 32);
            short4v a1h = *(const short4v*)(Ab + 36);
            short8 a0 = {a0l[0],a0l[1],a0l[2],a0l[3],a0h[0],a0h[1],a0h[2],a0h[3]};
            short8 a1 = {a1l[0],a1l[1],a1l[2],a1l[3],a1h[0],a1h[1],a1h[2],a1h[3]};
            f32x4 acc = {0.f, 0.f, 0.f, 0.f};
            acc = __builtin_amdgcn_mfma_f32_16x16x32_bf16(a0, bf0, acc, 0, 0, 0);
            acc = __builtin_amdgcn_mfma_f32_16x16x32_bf16(a1, bf1, acc, 0, 0, 0);
            const int t = t0 + q;                  // C row = q*4 + r -> t = q, vr = r
            __hip_bfloat16* yb = y + ((size_t)(n * T_ + t) * 25) * 64 + d;
            #pragma unroll
            for (int r = 0; r < 4; r++) {
                const int v = tau * 4 + r;
                if (v < 25) {
                    float val = acc[r] + bfl;
                    yb[v * 64] = __float2bfloat16(val);
                    ss[v] += val;
                    sq[v] = fmaf(val, val, sq[v]);
                }
            }
        }
    }
    // stats: reduce over q (4 lanes share same d & v-set), then 1 atomic/feature
    #pragma unroll
    for (int v = 0; v < 25; v++) {
        ss[v] += __shfl_xor(ss[v], 16); ss[v] += __shfl_xor(ss[v], 32);
        sq[v] += __shfl_xor(sq[v], 16); sq[v] += __shfl_xor(sq[v], 32);
    }
    if (q == 0) {
        float* sb = sn + (size_t)n * 3200;
        #pragma unroll
        for (int v = 0; v < 25; v++) {
            atomicAdd(&sb[v * 64 + d], ss[v]);
            atomicAdd(&sb[1600 + v * 64 + d], sq[v]);
        }
    }
}

// ---------------- K4: finalize BN -> ab[jo] = (scale, shift), jo = dd*25+vo ----------------
__global__ __launch_bounds__(256) void k_bn(
    const float* __restrict__ sn,
    const float* __restrict__ gamma, const float* __restrict__ beta,
    const int* __restrict__ shout,
    float2* __restrict__ ab)
{
    const int tid = threadIdx.x;
    const int jl = tid >> 2;                       // 0..63
    const int p  = tid & 3;                        // 0..3
    const int j = blockIdx.x * 64 + jl;            // z-feature j = vo*64 + dd
    const int src = shout[j];                      // y-feature vy*64 + dd
    float s = 0.f, qq = 0.f;
    for (int nn = p; nn < 128; nn += 4) {
        s  += sn[(size_t)nn * 3200 + src];
        qq += sn[(size_t)nn * 3200 + 1600 + src];
    }
    s  += __shfl_xor(s, 1);  s  += __shfl_xor(s, 2);
    qq += __shfl_xor(qq, 1); qq += __shfl_xor(qq, 2);
    if (p == 0) {
        const float invn = 1.0f / 32768.0f;
        float mu = s * invn;
        float var = qq * invn - mu * mu;
        float rstd = rsqrtf(var + 1e-5f);
        float a = gamma[j] * rstd;
        float bb = beta[j] - mu * a;
        int dd = j & 63, vo = j >> 6;
        ab[dd * 25 + vo] = make_float2(a, bb);     // output-layout order
    }
}

// ---------------- K5: y -> BN apply -> +x0 -> relu -> out[n,d,t,v] ----------------
// shift_out rotation: z[t,vo,dd] = y[t,(vo-dd)%25,dd]. 8-t slab (round-1 structure),
// 8 outputs/iteration for ILP. Cached x0 loads (x0 is L3-resident), NT stores.
__global__ __launch_bounds__(256, 6) void k_out(
    const __hip_bfloat16* __restrict__ y, const float* __restrict__ x0,
    const float2* __restrict__ ab, float* __restrict__ out)
{
    __shared__ __align__(16) unsigned short ys[8 * 1652];   // v-stride 66, t-stride 1652
    const int tid = threadIdx.x;
    const int n = blockIdx.x >> 5;
    const int t0 = (blockIdx.x & 31) * 8;
    const uint4* ysrc = (const uint4*)((const unsigned short*)y + (size_t)(n * T_ + t0) * 1600);
    for (int i = tid; i < 1600; i += 256) {        // stage y slab into padded LDS
        uint4 g = ysrc[i];
        int tl = i / 200, r8 = (i - tl * 200) * 8;
        int v = r8 >> 6, d0 = r8 & 63;
        unsigned* p = (unsigned*)ys + ((tl * 1652 + v * 66 + d0) >> 1);
        p[0] = g.x; p[1] = g.y; p[2] = g.z; p[3] = g.w;
    }
    __syncthreads();
    const float* xb = x0 + (size_t)n * CTV + t0 * 25;
    float* ob = out + (size_t)n * CTV + t0 * 25;
    for (int o8 = tid; o8 < 1600; o8 += 256) {     // o8 = dd*25 + chunk; 8 outputs/step
        int dd = o8 / 25;
        int rem8 = (o8 - dd * 25) * 8;             // 0..192, never crosses dd
        int ddm = dd;                              // dd mod 25
        if (ddm >= 25) ddm -= 25;
        if (ddm >= 25) ddm -= 25;
        int tl = rem8 / 25, vo = rem8 - tl * 25;
        const int base = dd * TV + rem8;
        f32x4 xv0 = *(const f32x4*)(xb + base);
        f32x4 xv1 = *(const f32x4*)(xb + base + 4);
        f32x4 r0, r1;
        #pragma unroll
        for (int e = 0; e < 8; e++) {
            int vy = vo - ddm; if (vy < 0) vy += 25;
            float val = b2f(ys[tl * 1652 + vy * 66 + dd]);
            float2 g = ab[dd * 25 + vo];
            float rr = fmaxf(fmaf(val, g.x, g.y) + ((e < 4) ? xv0[e] : xv1[e - 4]), 0.f);
            if (e < 4) r0[e] = rr; else r1[e - 4] = rr;
            vo++; if (vo == 25) { vo = 0; tl++; }
        }
        __builtin_nontemporal_store(r0, (f32x4*)(ob + base));
        __builtin_nontemporal_store(r1, (f32x4*)(ob + base + 4));
    }
}

extern "C" void kernel_launch(void* const* d_in, const int* in_sizes, int n_in,
                              void* d_out, int out_size, void* d_ws, size_t ws_size,
                              hipStream_t stream) {
    const float* x0    = (const float*)d_in[0];
    const int*   ep    = (const int*)  d_in[1];
    const float* fc1w  = (const float*)d_in[2];
    const float* fc1b  = (const float*)d_in[3];
    const float* fc2w  = (const float*)d_in[4];
    const float* fc2b  = (const float*)d_in[5];
    const float* Wm    = (const float*)d_in[6];
    const float* bm    = (const float*)d_in[7];
    const float* mask  = (const float*)d_in[8];
    const float* gamma = (const float*)d_in[9];
    const float* beta  = (const float*)d_in[10];
    const int*   shout = (const int*)  d_in[12];
    float* out = (float*)d_out;

    float* wsf = (float*)d_ws;
    float*          pooled = wsf;                        // 8192
    float*          bfv    = wsf + 8192;                 // 8192
    unsigned*       mgp    = (unsigned*)(wsf + 16384);   // 800
    float2*         ab     = (float2*)(wsf + 17984);     // 1600 float2 (3200 floats)
    unsigned short* Wfb    = (unsigned short*)(wsf + 22784);   // 524288 bf16 (262144 words)
    float*          sn     = wsf + 284928;               // 128*3200 = 409600
    __hip_bfloat16* y      = (__hip_bfloat16*)(wsf + 694528);  // 52,428,800 bf16
    unsigned short* xb16   = (unsigned short*)(wsf + 26908928); // 52,428,800 bf16 (105MB)

    hipMemsetAsync(sn, 0, 409600 * sizeof(float), stream);
    k_pool<<<N_ * C_, 256, 0, stream>>>(x0, pooled, xb16);
    k_se<<<N_, 256, 0, stream>>>(pooled, fc1w, fc1b, fc2w, fc2b, Wm, bm, mask,
                                 ep, Wfb, bfv, mgp);
    k_main<<<N_ * 16, 256, 0, stream>>>(xb16, Wfb, bfv, mgp, y, sn);
    k_bn<<<25, 256, 0, stream>>>(sn, gamma, beta, shout, ab);
    k_out<<<N_ * 32, 256, 0, stream>>>(y, x0, ab, out);
}

// Round 4
// 588.937 us; speedup vs baseline: 1.0379x; 1.0379x over previous
//
#include <hip/hip_runtime.h>
#include <hip/hip_bf16.h>
#include <math.h>

#define N_   128
#define C_   64
#define T_   256
#define V_   25
#define D_   64
#define CTV  409600   // C*T*V
#define TV   6400     // T*V

typedef __attribute__((ext_vector_type(8))) short short8;
typedef __attribute__((ext_vector_type(4))) short short4v;
typedef __attribute__((ext_vector_type(4))) float f32x4;

typedef __attribute__((address_space(1))) unsigned uag;
typedef __attribute__((address_space(3))) unsigned ual;
// global->LDS direct DMA, 16B per lane; LDS dest must be linear in lane order.
#define GLD16(gp, lp) __builtin_amdgcn_global_load_lds( \
    (uag*)(unsigned long long)(gp), (ual*)(unsigned)(unsigned long long)(lp), 16, 0, 0)

__device__ inline unsigned short f2b(float f) {
    __hip_bfloat16 h = __float2bfloat16(f);
    return *(unsigned short*)&h;
}
__device__ inline float b2f(unsigned short u) {
    return __uint_as_float(((unsigned)u) << 16);
}

// ---------------- K1: pooled[n*64+c] = mean over (t,v); also emit bf16 pre-swizzled x ----------------
// xb16 layout: [n][chunk=t/4][c][tl*25+v]  -> each (n,chunk) slab = 64*100 u16 = 12800B contiguous.
__global__ __launch_bounds__(256) void k_pool(const float* __restrict__ x0,
                                              float* __restrict__ pooled,
                                              unsigned short* __restrict__ xb16) {
    const int bid = blockIdx.x;            // n*64 + c  (plane of 6400 contiguous floats)
    const int tid = threadIdx.x;
    const int n = bid >> 6, c = bid & 63;
    const float4* base = (const float4*)(x0 + (size_t)bid * TV);
    float s = 0.f;
    for (int i = tid; i < 1600; i += 256) {
        float4 f = base[i];
        s += (f.x + f.y) + (f.z + f.w);
        int flat = i * 4;                          // t*25+v, never crosses a 100-elem chunk row
        int chunk = flat / 100;
        int within = flat - chunk * 100;
        short4v pk = { (short)f2b(f.x), (short)f2b(f.y), (short)f2b(f.z), (short)f2b(f.w) };
        *(short4v*)(xb16 + ((size_t)((n * 64 + chunk) * 64 + c)) * 100 + within) = pk;
    }
    #pragma unroll
    for (int off = 32; off > 0; off >>= 1) s += __shfl_down(s, off);
    __shared__ float red[4];
    if ((tid & 63) == 0) red[tid >> 6] = s;
    __syncthreads();
    if (tid == 0) pooled[bid] = (red[0] + red[1] + red[2] + red[3]) * (1.0f / TV);
}

// ---------------- K2: SE gate -> Wfb (bf16, B-frag order), bfv; mask-pair precompute ----------------
__global__ __launch_bounds__(256) void k_se(
    const float* __restrict__ pooled, const float* __restrict__ fc1w,
    const float* __restrict__ fc1b,  const float* __restrict__ fc2w,
    const float* __restrict__ fc2b,  const float* __restrict__ Wm,
    const float* __restrict__ bm,    const float* __restrict__ mask,
    const int* __restrict__ ep,
    unsigned short* __restrict__ Wfb, float* __restrict__ bfv,
    unsigned* __restrict__ mgp)
{
    __shared__ float sp[64], sh[16], sl[4];
    __shared__ float wk[64 * 65];          // W[k] staged [c][d] padded (+1)
    const int tid = threadIdx.x, n = blockIdx.x;
    if (tid < 64) sp[tid] = pooled[n * 64 + tid];
    __syncthreads();
    if (tid < 16) {
        float s = fc1b[tid];
        #pragma unroll
        for (int c = 0; c < 64; c++) s = fmaf(sp[c], fc1w[tid * 64 + c], s);
        sh[tid] = fmaxf(s, 0.f);
    }
    __syncthreads();
    if (tid < 4) {
        float s = fc2b[tid];
        #pragma unroll
        for (int j = 0; j < 16; j++) s = fmaf(sh[j], fc2w[tid * 16 + j], s);
        sl[tid] = s;
    }
    __syncthreads();
    const int e = ep[0];
    const float tao = (e >= 60) ? 1.0f : (-(29.0f / 60.0f) * (float)e + 30.0f);
    const float it = 1.0f / tao;
    float l0 = sl[0] * it, l1 = sl[1] * it, l2 = sl[2] * it, l3 = sl[3] * it;
    float mx = fmaxf(fmaxf(l0, l1), fmaxf(l2, l3));
    float e0 = expf(l0 - mx), e1 = expf(l1 - mx), e2 = expf(l2 - mx), e3 = expf(l3 - mx);
    float inv = 1.0f / (e0 + e1 + e2 + e3);
    float ga[4] = {e0 * inv, e1 * inv, e2 * inv, e3 * inv};

    float accW[16];
    #pragma unroll
    for (int m = 0; m < 16; m++) accW[m] = 0.f;
    #pragma unroll
    for (int k = 0; k < 4; k++) {
        __syncthreads();
        for (int i = tid; i < 4096; i += 256)       // coalesced read of W[k] ([c][d])
            wk[(i >> 6) * 65 + (i & 63)] = Wm[k * 4096 + i];
        __syncthreads();
        #pragma unroll
        for (int m = 0; m < 16; m++) {
            int o = m * 256 + tid;                   // frag-order flat index
            int w  = o >> 10, s = (o >> 9) & 1;
            int ln = (o >> 3) & 63, j = o & 7;
            int c  = s * 32 + (ln >> 4) * 8 + j;
            int d  = w * 16 + (ln & 15);
            accW[m] = fmaf(ga[k], wk[c * 65 + d], accW[m]);
        }
    }
    #pragma unroll
    for (int m = 0; m < 16; m++)
        Wfb[(size_t)n * 4096 + m * 256 + tid] = f2b(accW[m]);   // coalesced shorts
    if (tid < 64)
        bfv[n * 64 + tid] = ga[0] * bm[tid] + ga[1] * bm[64 + tid] +
                            ga[2] * bm[128 + tid] + ga[3] * bm[192 + tid];
    if (n == 0) {
        for (int j2 = tid; j2 < 800; j2 += 256) {   // j2 = v*32 + cp, c = 2*cp
            int v = j2 >> 5, c = (j2 & 31) * 2;
            unsigned m0 = (unsigned)f2b(tanhf(mask[v * 64 + c]) + 1.0f);
            unsigned m1 = (unsigned)f2b(tanhf(mask[v * 64 + c + 1]) + 1.0f);
            mgp[j2] = (m1 << 16) | m0;
        }
    }
}

// ---------------- K3: MFMA main: y = rot-gather(xb16)*mg @ Wf + bf, + BN stats ----------------
// DMA staging from pre-swizzled xb16; next sub's DMA issued after gather barrier (hides under MFMA).
// shift-in gather: src v' = (v + c) mod 25, src c' = c  (closed-form rotation).
__global__ __launch_bounds__(256, 4) void k_main(
    const unsigned short* __restrict__ xb16, const unsigned short* __restrict__ Wfb,
    const float* __restrict__ bfv, const unsigned* __restrict__ mgp,
    __hip_bfloat16* __restrict__ y, float* __restrict__ sn)
{
    __shared__ __align__(16) unsigned short xs[6400];   // bf16 slab [c][tl*25+v] (4 t's), linear
    __shared__ unsigned short At[7616];    // A-tile: 112 rows x 68 (stride 68 kills conflicts)
    __shared__ unsigned mgS[800];          // packed mask bf16 pairs [v][cp]

    const int tid = threadIdx.x;
    const int w = tid >> 6, l = tid & 63, q = l >> 4, m = l & 15;
    const int n = blockIdx.x >> 4;
    const int tbase = (blockIdx.x & 15) * 16;
    const int chunk0 = (blockIdx.x & 15) * 4;

    // B fragments (held whole kernel) + bias
    short8 bf0 = *(const short8*)(Wfb + (size_t)n * 4096 + (w * 2 + 0) * 512 + l * 8);
    short8 bf1 = *(const short8*)(Wfb + (size_t)n * 4096 + (w * 2 + 1) * 512 + l * 8);
    const int d = w * 16 + m;
    const float bfl = bfv[n * 64 + d];

    for (int i = tid; i < 800; i += 256) mgS[i] = mgp[i];
    // zero the 12 pad rows (v = 25..27 image): rho = 96 + t*4 + vr, vr in 1..3
    for (int i = tid; i < 408; i += 256) {
        int rr = i / 34, wo = i - rr * 34;
        int t = rr / 3, vr = rr - t * 3 + 1;
        ((unsigned*)At)[(96 + t * 4 + vr) * 34 + wo] = 0u;
    }
    {   // prologue: DMA sub 0 (12800B contiguous -> xs linear)
        const unsigned short* slab = xb16 + (size_t)(n * 64 + chunk0) * 6400;
        for (int i = tid; i < 800; i += 256)
            GLD16((const unsigned*)slab + i * 4, (unsigned*)xs + i * 4);
    }

    float ss[25], sq[25];
    #pragma unroll
    for (int v = 0; v < 25; v++) { ss[v] = 0.f; sq[v] = 0.f; }

    for (int sub = 0; sub < 4; sub++) {
        const int t0 = tbase + sub * 4;
        __syncthreads();   // xs(sub) DMA drained (vmcnt0 before barrier); prev At consumed
        // rotation gather + mask -> At (bf16 pairs)
        for (int p = tid; p < 3200; p += 256) {
            int cp = p & 31, rv = p >> 5;          // rv = t*25 + v
            int t = rv / 25, v = rv - t * 25;
            int c = cp * 2;
            unsigned mg = mgS[v * 32 + cp];
            int v0 = (v + c) % 25;
            int v1 = v0 + 1; if (v1 == 25) v1 = 0;
            float x0v = b2f(xs[c * 100 + t * 25 + v0])       * b2f((unsigned short)(mg & 0xffff));
            float x1v = b2f(xs[(c + 1) * 100 + t * 25 + v1]) * b2f((unsigned short)(mg >> 16));
            int rho = (v >> 2) * 16 + t * 4 + (v & 3);
            *(unsigned*)&At[rho * 68 + c] = ((unsigned)f2b(x1v) << 16) | f2b(x0v);
        }
        __syncthreads();   // At ready; xs free -> prefetch next slab under MFMA
        if (sub < 3) {
            const unsigned short* slab = xb16 + (size_t)(n * 64 + chunk0 + sub + 1) * 6400;
            for (int i = tid; i < 800; i += 256)
                GLD16((const unsigned*)slab + i * 4, (unsigned*)xs + i * 4);
        }
        // MFMA: 7 M-tiles x 2 k-steps; epilogue per tile
        #pragma unroll
        for (int tau = 0; tau < 7; tau++) {
            const unsigned short* Ab = At + (tau * 16 + m) * 68 + q * 8;
            short4v a0l = *(const short4v*)(Ab);
            short4v a0h = *(const short4v*)(Ab + 4);
            short4v a1l = *(const short4v*)(Ab + 32);
            short4v a1h = *(const short4v*)(Ab + 36);
            short8 a0 = {a0l[0],a0l[1],a0l[2],a0l[3],a0h[0],a0h[1],a0h[2],a0h[3]};
            short8 a1 = {a1l[0],a1l[1],a1l[2],a1l[3],a1h[0],a1h[1],a1h[2],a1h[3]};
            f32x4 acc = {0.f, 0.f, 0.f, 0.f};
            acc = __builtin_amdgcn_mfma_f32_16x16x32_bf16(a0, bf0, acc, 0, 0, 0);
            acc = __builtin_amdgcn_mfma_f32_16x16x32_bf16(a1, bf1, acc, 0, 0, 0);
            const int t = t0 + q;                  // C row = q*4 + r -> t = q, vr = r
            __hip_bfloat16* yb = y + ((size_t)(n * T_ + t) * 25) * 64 + d;
            #pragma unroll
            for (int r = 0; r < 4; r++) {
                const int v = tau * 4 + r;
                if (v < 25) {
                    float val = acc[r] + bfl;
                    yb[v * 64] = __float2bfloat16(val);
                    ss[v] += val;
                    sq[v] = fmaf(val, val, sq[v]);
                }
            }
        }
    }
    // stats: reduce over q (4 lanes share same d & v-set), then 1 atomic/feature
    #pragma unroll
    for (int v = 0; v < 25; v++) {
        ss[v] += __shfl_xor(ss[v], 16); ss[v] += __shfl_xor(ss[v], 32);
        sq[v] += __shfl_xor(sq[v], 16); sq[v] += __shfl_xor(sq[v], 32);
    }
    if (q == 0) {
        float* sb = sn + (size_t)n * 3200;
        #pragma unroll
        for (int v = 0; v < 25; v++) {
            atomicAdd(&sb[v * 64 + d], ss[v]);
            atomicAdd(&sb[1600 + v * 64 + d], sq[v]);
        }
    }
}

// ---------------- K4: finalize BN -> ab[jo] = (scale, shift), jo = dd*25+vo ----------------
__global__ __launch_bounds__(256) void k_bn(
    const float* __restrict__ sn,
    const float* __restrict__ gamma, const float* __restrict__ beta,
    const int* __restrict__ shout,
    float2* __restrict__ ab)
{
    const int tid = threadIdx.x;
    const int jl = tid >> 2;                       // 0..63
    const int p  = tid & 3;                        // 0..3
    const int j = blockIdx.x * 64 + jl;            // z-feature j = vo*64 + dd
    const int src = shout[j];                      // y-feature vy*64 + dd
    float s = 0.f, qq = 0.f;
    for (int nn = p; nn < 128; nn += 4) {
        s  += sn[(size_t)nn * 3200 + src];
        qq += sn[(size_t)nn * 3200 + 1600 + src];
    }
    s  += __shfl_xor(s, 1);  s  += __shfl_xor(s, 2);
    qq += __shfl_xor(qq, 1); qq += __shfl_xor(qq, 2);
    if (p == 0) {
        const float invn = 1.0f / 32768.0f;
        float mu = s * invn;
        float var = qq * invn - mu * mu;
        float rstd = rsqrtf(var + 1e-5f);
        float a = gamma[j] * rstd;
        float bb = beta[j] - mu * a;
        int dd = j & 63, vo = j >> 6;
        ab[dd * 25 + vo] = make_float2(a, bb);     // output-layout order
    }
}

// ---------------- K5: y -> BN apply -> +x0 -> relu -> out[n,d,t,v]  (round-1 verified form) ----------------
// shift_out rotation: z[t,vo,dd] = y[t,(vo-dd)%25,dd]. 8-t slab, o4 loop: 50 lanes cover one
// dd-plane's 800B contiguously per store. Cached x0 loads (L3-resident), NT stores.
__global__ __launch_bounds__(256, 6) void k_out(
    const __hip_bfloat16* __restrict__ y, const float* __restrict__ x0,
    const float2* __restrict__ ab, float* __restrict__ out)
{
    __shared__ __align__(16) unsigned short ys[8 * 1652];   // v-stride 66, t-stride 1652
    const int tid = threadIdx.x;
    const int n = blockIdx.x >> 5;
    const int t0 = (blockIdx.x & 31) * 8;
    const uint4* ysrc = (const uint4*)((const unsigned short*)y + (size_t)(n * T_ + t0) * 1600);
    for (int i = tid; i < 1600; i += 256) {        // stage y slab into padded LDS
        uint4 g = ysrc[i];
        int tl = i / 200, r8 = (i - tl * 200) * 8;
        int v = r8 >> 6, d0 = r8 & 63;
        unsigned* p = (unsigned*)ys + ((tl * 1652 + v * 66 + d0) >> 1);
        p[0] = g.x; p[1] = g.y; p[2] = g.z; p[3] = g.w;
    }
    __syncthreads();
    const float* xb = x0 + (size_t)n * CTV + t0 * 25;
    float* ob = out + (size_t)n * CTV + t0 * 25;
    for (int o4 = tid; o4 < 3200; o4 += 256) {     // 4 consecutive outputs per step
        int dd = o4 / 50;
        int rem4 = (o4 - dd * 50) * 4;             // 0..196, never crosses dd
        int ddm = dd;                              // dd mod 25
        if (ddm >= 25) ddm -= 25;
        if (ddm >= 25) ddm -= 25;
        int tl = rem4 / 25, vo = rem4 - tl * 25;
        const int base = dd * TV + rem4;
        f32x4 xv = *(const f32x4*)(xb + base);
        f32x4 r;
        #pragma unroll
        for (int e = 0; e < 4; e++) {
            int vy = vo - ddm; if (vy < 0) vy += 25;
            float val = b2f(ys[tl * 1652 + vy * 66 + dd]);
            float2 g = ab[dd * 25 + vo];
            r[e] = fmaxf(fmaf(val, g.x, g.y) + xv[e], 0.f);
            vo++; if (vo == 25) { vo = 0; tl++; }
        }
        __builtin_nontemporal_store(r, (f32x4*)(ob + base));
    }
}

extern "C" void kernel_launch(void* const* d_in, const int* in_sizes, int n_in,
                              void* d_out, int out_size, void* d_ws, size_t ws_size,
                              hipStream_t stream) {
    const float* x0    = (const float*)d_in[0];
    const int*   ep    = (const int*)  d_in[1];
    const float* fc1w  = (const float*)d_in[2];
    const float* fc1b  = (const float*)d_in[3];
    const float* fc2w  = (const float*)d_in[4];
    const float* fc2b  = (const float*)d_in[5];
    const float* Wm    = (const float*)d_in[6];
    const float* bm    = (const float*)d_in[7];
    const float* mask  = (const float*)d_in[8];
    const float* gamma = (const float*)d_in[9];
    const float* beta  = (const float*)d_in[10];
    const int*   shout = (const int*)  d_in[12];
    float* out = (float*)d_out;

    float* wsf = (float*)d_ws;
    float*          pooled = wsf;                        // 8192
    float*          bfv    = wsf + 8192;                 // 8192
    unsigned*       mgp    = (unsigned*)(wsf + 16384);   // 800
    float2*         ab     = (float2*)(wsf + 17984);     // 1600 float2 (3200 floats)
    unsigned short* Wfb    = (unsigned short*)(wsf + 22784);   // 524288 bf16 (262144 words)
    float*          sn     = wsf + 284928;               // 128*3200 = 409600
    __hip_bfloat16* y      = (__hip_bfloat16*)(wsf + 694528);  // 52,428,800 bf16
    unsigned short* xb16   = (unsigned short*)(wsf + 26908928); // 52,428,800 bf16 (105MB)

    hipMemsetAsync(sn, 0, 409600 * sizeof(float), stream);
    k_pool<<<N_ * C_, 256, 0, stream>>>(x0, pooled, xb16);
    k_se<<<N_, 256, 0, stream>>>(pooled, fc1w, fc1b, fc2w, fc2b, Wm, bm, mask,
                                 ep, Wfb, bfv, mgp);
    k_main<<<N_ * 16, 256, 0, stream>>>(xb16, Wfb, bfv, mgp, y, sn);
    k_bn<<<25, 256, 0, stream>>>(sn, gamma, beta, shout, ab);
    k_out<<<N_ * 32, 256, 0, stream>>>(y, x0, ab, out);
}

// Round 5
// 573.748 us; speedup vs baseline: 1.0654x; 1.0265x over previous
//
#include <hip/hip_runtime.h>
#include <hip/hip_bf16.h>
#include <math.h>

#define N_   128
#define C_   64
#define T_   256
#define V_   25
#define D_   64
#define CTV  409600   // C*T*V
#define TV   6400     // T*V

typedef __attribute__((ext_vector_type(8))) short short8;
typedef __attribute__((ext_vector_type(4))) short short4v;
typedef __attribute__((ext_vector_type(4))) float f32x4;

__device__ inline unsigned short f2b(float f) {
    __hip_bfloat16 h = __float2bfloat16(f);
    return *(unsigned short*)&h;
}
__device__ inline float b2f(unsigned short u) {
    return __uint_as_float(((unsigned)u) << 16);
}

// ---------------- K1: pooled[n*64+c] = mean over (t,v) ----------------
__global__ __launch_bounds__(256) void k_pool(const float* __restrict__ x0,
                                              float* __restrict__ pooled) {
    const int bid = blockIdx.x;            // n*64 + c  (plane of 6400 contiguous floats)
    const int tid = threadIdx.x;
    const float4* base = (const float4*)(x0 + (size_t)bid * TV);
    float s = 0.f;
    for (int i = tid; i < 1600; i += 256) {
        float4 f = base[i];
        s += (f.x + f.y) + (f.z + f.w);
    }
    #pragma unroll
    for (int off = 32; off > 0; off >>= 1) s += __shfl_down(s, off);
    __shared__ float red[4];
    if ((tid & 63) == 0) red[tid >> 6] = s;
    __syncthreads();
    if (tid == 0) pooled[bid] = (red[0] + red[1] + red[2] + red[3]) * (1.0f / TV);
}

// ---------------- K2: SE gate -> Wfb (bf16, B-frag order), bfv; mask table [c][v] ----------------
// Wfb[n] flat index e = ((w*2+s)*64 + lane)*8 + j  <->  B[c = s*32 + (lane>>4)*8 + j][d = w*16 + (lane&15)]
__global__ __launch_bounds__(256) void k_se(
    const float* __restrict__ pooled, const float* __restrict__ fc1w,
    const float* __restrict__ fc1b,  const float* __restrict__ fc2w,
    const float* __restrict__ fc2b,  const float* __restrict__ Wm,
    const float* __restrict__ bm,    const float* __restrict__ mask,
    const int* __restrict__ ep,
    unsigned short* __restrict__ Wfb, float* __restrict__ bfv,
    unsigned short* __restrict__ mgT)
{
    __shared__ float sp[64], sh[16], sl[4];
    __shared__ float wk[64 * 65];          // W[k] staged [c][d] padded (+1)
    const int tid = threadIdx.x, n = blockIdx.x;
    if (tid < 64) sp[tid] = pooled[n * 64 + tid];
    __syncthreads();
    if (tid < 16) {
        float s = fc1b[tid];
        #pragma unroll
        for (int c = 0; c < 64; c++) s = fmaf(sp[c], fc1w[tid * 64 + c], s);
        sh[tid] = fmaxf(s, 0.f);
    }
    __syncthreads();
    if (tid < 4) {
        float s = fc2b[tid];
        #pragma unroll
        for (int j = 0; j < 16; j++) s = fmaf(sh[j], fc2w[tid * 16 + j], s);
        sl[tid] = s;
    }
    __syncthreads();
    const int e = ep[0];
    const float tao = (e >= 60) ? 1.0f : (-(29.0f / 60.0f) * (float)e + 30.0f);
    const float it = 1.0f / tao;
    float l0 = sl[0] * it, l1 = sl[1] * it, l2 = sl[2] * it, l3 = sl[3] * it;
    float mx = fmaxf(fmaxf(l0, l1), fmaxf(l2, l3));
    float e0 = expf(l0 - mx), e1 = expf(l1 - mx), e2 = expf(l2 - mx), e3 = expf(l3 - mx);
    float inv = 1.0f / (e0 + e1 + e2 + e3);
    float ga[4] = {e0 * inv, e1 * inv, e2 * inv, e3 * inv};

    float accW[16];
    #pragma unroll
    for (int m = 0; m < 16; m++) accW[m] = 0.f;
    #pragma unroll
    for (int k = 0; k < 4; k++) {
        __syncthreads();
        for (int i = tid; i < 4096; i += 256)       // coalesced read of W[k] ([c][d])
            wk[(i >> 6) * 65 + (i & 63)] = Wm[k * 4096 + i];
        __syncthreads();
        #pragma unroll
        for (int m = 0; m < 16; m++) {
            int o = m * 256 + tid;                   // frag-order flat index
            int w  = o >> 10, s = (o >> 9) & 1;
            int ln = (o >> 3) & 63, j = o & 7;
            int c  = s * 32 + (ln >> 4) * 8 + j;
            int d  = w * 16 + (ln & 15);
            accW[m] = fmaf(ga[k], wk[c * 65 + d], accW[m]);
        }
    }
    #pragma unroll
    for (int m = 0; m < 16; m++)
        Wfb[(size_t)n * 4096 + m * 256 + tid] = f2b(accW[m]);   // coalesced shorts
    if (tid < 64)
        bfv[n * 64 + tid] = ga[0] * bm[tid] + ga[1] * bm[64 + tid] +
                            ga[2] * bm[128 + tid] + ga[3] * bm[192 + tid];
    if (n == 0) {
        for (int i = tid; i < 1600; i += 256) {     // i = c*25 + v  (transposed mask table)
            int c = i / 25, v = i - c * 25;
            mgT[i] = f2b(tanhf(mask[v * 64 + c]) + 1.0f);
        }
    }
}

// ---------------- K3: MFMA main (fused stage): y = rot-gather(x0)*mg @ Wf + bf, + BN stats ----------------
// Fused staging: load x0 float4, mask-multiply, convert once, scatter u16 straight into the
// rotated A-tile position (v = (v'-c) mod 25, rho = (v>>2)*16 + t*4 + (v&3), col = c).
// Double-buffered At -> 1 barrier per sub-chunk. WAR on At[p] is closed because a wave reaches
// stage(sub+2) only after barrier(sub+1), which all waves pass only after mfma(sub) completed.
__global__ __launch_bounds__(256, 4) void k_main(
    const float* __restrict__ x0, const unsigned short* __restrict__ Wfb,
    const float* __restrict__ bfv, const unsigned short* __restrict__ mgT,
    __hip_bfloat16* __restrict__ y, float* __restrict__ sn)
{
    __shared__ unsigned short At[2][7616];  // A-tile dbuf: 112 rows x 68 (stride 68 kills conflicts)
    __shared__ unsigned short mgTs[64 * 26]; // mask bf16 [c][v], v-stride 26

    const int tid = threadIdx.x;
    const int w = tid >> 6, l = tid & 63, q = l >> 4, m = l & 15;
    const int n = blockIdx.x >> 4;
    const int tbase = (blockIdx.x & 15) * 16;

    // B fragments (held whole kernel) + bias
    short8 bf0 = *(const short8*)(Wfb + (size_t)n * 4096 + (w * 2 + 0) * 512 + l * 8);
    short8 bf1 = *(const short8*)(Wfb + (size_t)n * 4096 + (w * 2 + 1) * 512 + l * 8);
    const int d = w * 16 + m;
    const float bfl = bfv[n * 64 + d];

    for (int i = tid; i < 1600; i += 256) {
        int c = i / 25, v = i - c * 25;
        mgTs[c * 26 + v] = mgT[i];
    }
    // zero the 12 pad rows (v image 25..27) in BOTH buffers: rho = 96 + t*4 + vr, vr in 1..3
    for (int i = tid; i < 816; i += 256) {
        int b = (i >= 408) ? 1 : 0;
        int ii = i - b * 408;
        int rr = ii / 34, wo = ii - rr * 34;
        int t = rr / 3, vr = rr - t * 3 + 1;
        ((unsigned*)At[b])[(96 + t * 4 + vr) * 34 + wo] = 0u;
    }
    __syncthreads();   // mgTs + pad rows visible

    float ss[25], sq[25];
    #pragma unroll
    for (int v = 0; v < 25; v++) { ss[v] = 0.f; sq[v] = 0.f; }

    const float4* src = (const float4*)x0;
    for (int sub = 0; sub < 4; sub++) {
        const int t0 = tbase + sub * 4;
        unsigned short* Ab = At[sub & 1];
        const int fb = n * 102400 + (t0 * 25) / 4;   // t0 % 4 == 0
        for (int i = tid; i < 1600; i += 256) {      // per c: 100 floats (25 float4) = 4 t's
            int c = i / 25, r = i - c * 25;
            float4 f = src[fb + c * 1600 + r];
            int cm = c; if (cm >= 25) cm -= 25; if (cm >= 25) cm -= 25;
            int f0 = r * 4;                          // flat = t*25 + v'
            int t = f0 / 25;
            int vp = f0 - t * 25;                    // v' (source joint)
            int v = vp - cm; if (v < 0) v += 25;     // output joint
            #pragma unroll
            for (int e = 0; e < 4; e++) {
                float xv = (e == 0) ? f.x : (e == 1) ? f.y : (e == 2) ? f.z : f.w;
                int rho = (v >> 2) * 16 + t * 4 + (v & 3);
                Ab[rho * 68 + c] = f2b(xv * b2f(mgTs[c * 26 + v]));
                vp++; v++;
                if (vp == 25) { vp = 0; t++; }
                if (v == 25) v = 0;
            }
        }
        __syncthreads();   // At[sub&1] ready (next sub stages the other buffer under our MFMA)
        // MFMA: 7 M-tiles x 2 k-steps; epilogue per tile
        #pragma unroll
        for (int tau = 0; tau < 7; tau++) {
            const unsigned short* Abr = Ab + (tau * 16 + m) * 68 + q * 8;
            short4v a0l = *(const short4v*)(Abr);
            short4v a0h = *(const short4v*)(Abr + 4);
            short4v a1l = *(const short4v*)(Abr + 32);
            short4v a1h = *(const short4v*)(Abr + 36);
            short8 a0 = {a0l[0],a0l[1],a0l[2],a0l[3],a0h[0],a0h[1],a0h[2],a0h[3]};
            short8 a1 = {a1l[0],a1l[1],a1l[2],a1l[3],a1h[0],a1h[1],a1h[2],a1h[3]};
            f32x4 acc = {0.f, 0.f, 0.f, 0.f};
            acc = __builtin_amdgcn_mfma_f32_16x16x32_bf16(a0, bf0, acc, 0, 0, 0);
            acc = __builtin_amdgcn_mfma_f32_16x16x32_bf16(a1, bf1, acc, 0, 0, 0);
            const int t = t0 + q;                  // C row = q*4 + r -> t = q, vr = r
            __hip_bfloat16* yb = y + ((size_t)(n * T_ + t) * 25) * 64 + d;
            #pragma unroll
            for (int r = 0; r < 4; r++) {
                const int v = tau * 4 + r;
                if (v < 25) {
                    float val = acc[r] + bfl;
                    yb[v * 64] = __float2bfloat16(val);
                    ss[v] += val;
                    sq[v] = fmaf(val, val, sq[v]);
                }
            }
        }
    }
    // stats: reduce over q (4 lanes share same d & v-set), then 1 atomic/feature
    #pragma unroll
    for (int v = 0; v < 25; v++) {
        ss[v] += __shfl_xor(ss[v], 16); ss[v] += __shfl_xor(ss[v], 32);
        sq[v] += __shfl_xor(sq[v], 16); sq[v] += __shfl_xor(sq[v], 32);
    }
    if (q == 0) {
        float* sb = sn + (size_t)n * 3200;
        #pragma unroll
        for (int v = 0; v < 25; v++) {
            atomicAdd(&sb[v * 64 + d], ss[v]);
            atomicAdd(&sb[1600 + v * 64 + d], sq[v]);
        }
    }
}

// ---------------- K4: finalize BN -> ab[jo] = (scale, shift), jo = dd*25+vo ----------------
__global__ __launch_bounds__(256) void k_bn(
    const float* __restrict__ sn,
    const float* __restrict__ gamma, const float* __restrict__ beta,
    const int* __restrict__ shout,
    float2* __restrict__ ab)
{
    const int tid = threadIdx.x;
    const int jl = tid >> 2;                       // 0..63
    const int p  = tid & 3;                        // 0..3
    const int j = blockIdx.x * 64 + jl;            // z-feature j = vo*64 + dd
    const int src = shout[j];                      // y-feature vy*64 + dd
    float s = 0.f, qq = 0.f;
    for (int nn = p; nn < 128; nn += 4) {
        s  += sn[(size_t)nn * 3200 + src];
        qq += sn[(size_t)nn * 3200 + 1600 + src];
    }
    s  += __shfl_xor(s, 1);  s  += __shfl_xor(s, 2);
    qq += __shfl_xor(qq, 1); qq += __shfl_xor(qq, 2);
    if (p == 0) {
        const float invn = 1.0f / 32768.0f;
        float mu = s * invn;
        float var = qq * invn - mu * mu;
        float rstd = rsqrtf(var + 1e-5f);
        float a = gamma[j] * rstd;
        float bb = beta[j] - mu * a;
        int dd = j & 63, vo = j >> 6;
        ab[dd * 25 + vo] = make_float2(a, bb);     // output-layout order
    }
}

// ---------------- K5: y -> BN apply -> +x0 -> relu -> out[n,d,t,v]  (round-1 verified form) ----------------
// shift_out rotation: z[t,vo,dd] = y[t,(vo-dd)%25,dd]. 8-t slab, o4 loop: 50 lanes cover one
// dd-plane's 800B contiguously per store. Cached x0 loads (L3-resident), NT stores.
__global__ __launch_bounds__(256, 6) void k_out(
    const __hip_bfloat16* __restrict__ y, const float* __restrict__ x0,
    const float2* __restrict__ ab, float* __restrict__ out)
{
    __shared__ __align__(16) unsigned short ys[8 * 1652];   // v-stride 66, t-stride 1652
    const int tid = threadIdx.x;
    const int n = blockIdx.x >> 5;
    const int t0 = (blockIdx.x & 31) * 8;
    const uint4* ysrc = (const uint4*)((const unsigned short*)y + (size_t)(n * T_ + t0) * 1600);
    for (int i = tid; i < 1600; i += 256) {        // stage y slab into padded LDS
        uint4 g = ysrc[i];
        int tl = i / 200, r8 = (i - tl * 200) * 8;
        int v = r8 >> 6, d0 = r8 & 63;
        unsigned* p = (unsigned*)ys + ((tl * 1652 + v * 66 + d0) >> 1);
        p[0] = g.x; p[1] = g.y; p[2] = g.z; p[3] = g.w;
    }
    __syncthreads();
    const float* xb = x0 + (size_t)n * CTV + t0 * 25;
    float* ob = out + (size_t)n * CTV + t0 * 25;
    for (int o4 = tid; o4 < 3200; o4 += 256) {     // 4 consecutive outputs per step
        int dd = o4 / 50;
        int rem4 = (o4 - dd * 50) * 4;             // 0..196, never crosses dd
        int ddm = dd;                              // dd mod 25
        if (ddm >= 25) ddm -= 25;
        if (ddm >= 25) ddm -= 25;
        int tl = rem4 / 25, vo = rem4 - tl * 25;
        const int base = dd * TV + rem4;
        f32x4 xv = *(const f32x4*)(xb + base);
        f32x4 r;
        #pragma unroll
        for (int e = 0; e < 4; e++) {
            int vy = vo - ddm; if (vy < 0) vy += 25;
            float val = b2f(ys[tl * 1652 + vy * 66 + dd]);
            float2 g = ab[dd * 25 + vo];
            r[e] = fmaxf(fmaf(val, g.x, g.y) + xv[e], 0.f);
            vo++; if (vo == 25) { vo = 0; tl++; }
        }
        __builtin_nontemporal_store(r, (f32x4*)(ob + base));
    }
}

extern "C" void kernel_launch(void* const* d_in, const int* in_sizes, int n_in,
                              void* d_out, int out_size, void* d_ws, size_t ws_size,
                              hipStream_t stream) {
    const float* x0    = (const float*)d_in[0];
    const int*   ep    = (const int*)  d_in[1];
    const float* fc1w  = (const float*)d_in[2];
    const float* fc1b  = (const float*)d_in[3];
    const float* fc2w  = (const float*)d_in[4];
    const float* fc2b  = (const float*)d_in[5];
    const float* Wm    = (const float*)d_in[6];
    const float* bm    = (const float*)d_in[7];
    const float* mask  = (const float*)d_in[8];
    const float* gamma = (const float*)d_in[9];
    const float* beta  = (const float*)d_in[10];
    const int*   shout = (const int*)  d_in[12];
    float* out = (float*)d_out;

    float* wsf = (float*)d_ws;
    float*          pooled = wsf;                        // 8192
    float*          bfv    = wsf + 8192;                 // 8192
    unsigned short* mgT    = (unsigned short*)(wsf + 16384);   // 1600 u16
    float2*         ab     = (float2*)(wsf + 17984);     // 1600 float2 (3200 floats)
    unsigned short* Wfb    = (unsigned short*)(wsf + 22784);   // 524288 bf16 (262144 words)
    float*          sn     = wsf + 284928;               // 128*3200 = 409600
    __hip_bfloat16* y      = (__hip_bfloat16*)(wsf + 694528);  // 52,428,800 bf16

    hipMemsetAsync(sn, 0, 409600 * sizeof(float), stream);
    k_pool<<<N_ * C_, 256, 0, stream>>>(x0, pooled);
    k_se<<<N_, 256, 0, stream>>>(pooled, fc1w, fc1b, fc2w, fc2b, Wm, bm, mask,
                                 ep, Wfb, bfv, mgT);
    k_main<<<N_ * 16, 256, 0, stream>>>(x0, Wfb, bfv, mgT, y, sn);
    k_bn<<<25, 256, 0, stream>>>(sn, gamma, beta, shout, ab);
    k_out<<<N_ * 32, 256, 0, stream>>>(y, x0, ab, out);
}